// Round 6
// baseline (205.584 us; speedup 1.0000x reference)
//
#include <hip/hip_runtime.h>

#define N     4096
#define FIN   256
#define CC    256   // HEADS * F_OUT
#define HEADS 4
#define FOUT  64
#define XPITCH 266  // FIN+10 shorts = 133 dwords (odd) -> conflict-free
#define HPITCH 74   // 37 dwords (odd)

typedef __attribute__((ext_vector_type(8))) short bf16x8;
typedef __attribute__((ext_vector_type(4))) float f32x4;

// float -> bf16 (round-nearest-even)
__device__ inline short f2bf(float f) {
    unsigned u = __builtin_bit_cast(unsigned, f);
    unsigned r = u + 0x7fffu + ((u >> 16) & 1u);
    return (short)(r >> 16);
}

// Kernel 1, fused:
//   blocks [0,256):    h = x@W via MFMA (one head x 64 n-rows) -> hF in
//                      fragment order + e1T/e2T wave-reduced.
//   blocks [256,1280): adj -> bitmask adjb (batched int4 loads, shfl packing).
__global__ __launch_bounds__(256) void gat_k1(const float* __restrict__ x,
                                              const float* __restrict__ W,
                                              const float* __restrict__ a,
                                              const int* __restrict__ adj,
                                              short* __restrict__ hF,
                                              float* __restrict__ e1T,
                                              float* __restrict__ e2T,
                                              unsigned* __restrict__ adjb) {
    __shared__ __align__(16) short xs[64][XPITCH];    // 34.0 KB
    __shared__ __align__(16) short wts[64][XPITCH];   // 34.0 KB
    __shared__ __align__(16) short hbuf[64][HPITCH];  //  9.5 KB
    const int t    = threadIdx.x;
    const int bid  = blockIdx.x;
    const int lane = t & 63;
    const int w    = t >> 6;

    if (bid >= 256) {
        // ---- adj bitmask pack: one row per wave ----
        const int row = (bid - 256) * 4 + w;
        const int4* arow4 = (const int4*)(adj + (size_t)row * N);
        unsigned* drow = adjb + (size_t)row * 128;
        #pragma unroll
        for (int p4 = 0; p4 < 4; ++p4) {
            int4 ca[4];
            #pragma unroll
            for (int k = 0; k < 4; ++k)
                ca[k] = arow4[(p4 * 4 + k) * 64 + lane];   // 4 loads in flight
            #pragma unroll
            for (int k = 0; k < 4; ++k) {
                const int4 v = ca[k];
                unsigned n = (v.x != 0 ? 1u : 0u) | (v.y != 0 ? 2u : 0u) |
                             (v.z != 0 ? 4u : 0u) | (v.w != 0 ? 8u : 0u);
                unsigned b  = n   | ((unsigned)__shfl_xor((int)n,   1, 64) << 4);
                unsigned hw = b   | ((unsigned)__shfl_xor((int)b,   2, 64) << 8);
                unsigned d  = hw  | ((unsigned)__shfl_xor((int)hw,  4, 64) << 16);
                if ((lane & 7) == 0) drow[(p4 * 4 + k) * 8 + (lane >> 3)] = d;
            }
        }
        return;
    }

    // ---- GEMM block ----
    const int hd = bid >> 6;
    const int n0 = (bid & 63) * 64;
    const int c0 = hd * 64;

    {   // stage x rows n0..n0+63 as bf16
        const float4* xsrc = (const float4*)(x + (size_t)n0 * FIN);
        #pragma unroll
        for (int it = 0; it < 16; ++it) {
            const int fi = it * 256 + t;
            const float4 v = xsrc[fi];
            short4 o;
            o.x = f2bf(v.x); o.y = f2bf(v.y); o.z = f2bf(v.z); o.w = f2bf(v.w);
            *(short4*)&xs[fi >> 6][(fi & 63) * 4] = o;
        }
    }
    {   // stage W^T column slice
        const int c  = t & 63;
        const int k4 = (t >> 6) * 4;
        #pragma unroll
        for (int it = 0; it < 16; ++it) {
            const int k = it * 16 + k4;
            short4 pk;
            pk.x = f2bf(W[(k + 0) * CC + c0 + c]);
            pk.y = f2bf(W[(k + 1) * CC + c0 + c]);
            pk.z = f2bf(W[(k + 2) * CC + c0 + c]);
            pk.w = f2bf(W[(k + 3) * CC + c0 + c]);
            *(short4*)&wts[c][k] = pk;
        }
    }
    __syncthreads();

    const int m = lane & 15;
    const int q = lane >> 4;

    f32x4 acc[4];
    #pragma unroll
    for (int ct = 0; ct < 4; ++ct) acc[ct] = (f32x4){0.f, 0.f, 0.f, 0.f};

    #pragma unroll
    for (int ks = 0; ks < 8; ++ks) {
        const bf16x8 af = *(const bf16x8*)&xs[w * 16 + m][ks * 32 + q * 8];
        #pragma unroll
        for (int ct = 0; ct < 4; ++ct) {
            const bf16x8 bf_ = *(const bf16x8*)&wts[ct * 16 + m][ks * 32 + q * 8];
            acc[ct] = __builtin_amdgcn_mfma_f32_16x16x32_bf16(af, bf_, acc[ct], 0, 0, 0);
        }
    }

    // e1/e2 from fp32 acc (C layout: row=q*4+r, col=ct*16+m)
    const float a1v[4] = {a[m], a[16 + m], a[32 + m], a[48 + m]};
    const float a2v[4] = {a[64 + m], a[80 + m], a[96 + m], a[112 + m]};
    #pragma unroll
    for (int r = 0; r < 4; ++r) {
        float s1 = 0.f, s2 = 0.f;
        #pragma unroll
        for (int ct = 0; ct < 4; ++ct) {
            s1 = fmaf(acc[ct][r], a1v[ct], s1);
            s2 = fmaf(acc[ct][r], a2v[ct], s2);
        }
        #pragma unroll
        for (int sh = 1; sh < 16; sh <<= 1) {
            s1 += __shfl_xor(s1, sh, 64);
            s2 += __shfl_xor(s2, sh, 64);
        }
        if (m == 0) {
            const int n = n0 + w * 16 + q * 4 + r;
            e1T[hd * N + n] = s1;
            e2T[hd * N + n] = s2;
        }
    }

    // transpose h tile to hbuf[c][n-local]
    #pragma unroll
    for (int ct = 0; ct < 4; ++ct)
        #pragma unroll
        for (int r = 0; r < 4; ++r)
            hbuf[ct * 16 + m][w * 16 + q * 4 + r] = f2bf(acc[ct][r]);
    __syncthreads();

    // write hF in fragment order: frag(jc, ft) lane lp holds
    // h[f=ft*16+(lp&15)][j = jc*32 + (lp>>4)*8 + 0..7]
    {
        const int lp = t & 63;
        const int ft = t >> 6;
        const int mm = lp & 15;
        const int qq = lp >> 4;
        #pragma unroll
        for (int c2 = 0; c2 < 2; ++c2) {
            const bf16x8 hv = *(const bf16x8*)&hbuf[ft * 16 + mm][c2 * 32 + qq * 8];
            const size_t jc = (size_t)(n0 >> 5) + c2;
            *(bf16x8*)(hF + ((((size_t)hd * 128 + jc) * 4 + ft) * 64 + lp) * 8) = hv;
        }
    }
}

// Kernel 2: masked-softmax aggregation via MFMA. 16 i-rows, one head,
// HALF the j-range per block -> grid 2048 (8 blocks per i-tile; bid&255
// keeps sharers on one XCD). 8 waves = 8 j-stripes of the half. Partial
// numerator + Z written to EXCLUSIVE global slices (no atomics). VGPR-lean
// + 16.7 KB LDS -> 8 waves/EU, 32 waves/CU.
__global__ __launch_bounds__(512, 8) void gat_k2(const short* __restrict__ hF,
                                                 const unsigned* __restrict__ adjb,
                                                 const float* __restrict__ e1T,
                                                 const float* __restrict__ e2T,
                                                 float* __restrict__ nbuf,
                                                 float* __restrict__ zpart) {
    __shared__ float obuf[16][64];                // 4 KB
    __shared__ float zbuf[8][16];                 // 0.5 KB
    __shared__ __align__(16) float e2lds[2048];   // 8 KB (j-half)
    __shared__ unsigned adjlds[16 * 65];          // 4.2 KB (odd pitch)
    const int t    = threadIdx.x;
    const int lane = t & 63;
    const int g    = t >> 6;
    const int bid  = blockIdx.x;
    const int it   = bid & 255;               // i-tile; XCD = bid & 7
    const int sub  = bid >> 8;                // 0..7
    const int hd   = sub >> 1;
    const int jh   = sub & 1;                 // j-half
    const int i0   = it * 16;
    const int m    = lane & 15;
    const int q    = lane >> 4;

    {   float* ob = &obuf[0][0]; ob[t] = 0.f; ob[t + 512] = 0.f; }
    {   // stage e2 for this head's j-half
        const float4* src = (const float4*)(e2T + (size_t)hd * N + jh * 2048);
        ((float4*)e2lds)[t] = src[t];
    }
    {   // stage adj bits: 16 rows x 64 dwords of this j-half
        const unsigned* src = adjb + (size_t)i0 * 128 + jh * 64;
        #pragma unroll
        for (int rr = 0; rr < 2; ++rr) {
            const int idx = t + rr * 512;
            adjlds[(idx >> 6) * 65 + (idx & 63)] = src[(idx >> 6) * 128 + (idx & 63)];
        }
    }
    __syncthreads();

    const float e1v = e1T[hd * N + i0 + m];

    f32x4 accf[4];
    #pragma unroll
    for (int ft = 0; ft < 4; ++ft) accf[ft] = (f32x4){0.f, 0.f, 0.f, 0.f};
    float zacc = 0.f;

    // chunk jc = jh*64 + step*8 + g; layout hF[hd][jc][ft][lane][8]
    const short* hbase = hF + (((size_t)hd * 128 + jh * 64 + g) * 256 + lane) * 8;
    const unsigned char* abyte = ((const unsigned char*)adjlds) + m * 260 + g * 4 + q;

    for (int step = 0; step < 8; ++step) {
        const short* hstep = hbase + (size_t)step * 16384;
        const bf16x8 b0 = *(const bf16x8*)(hstep);
        const bf16x8 b1 = *(const bf16x8*)(hstep + 512);
        const bf16x8 b2 = *(const bf16x8*)(hstep + 1024);
        const bf16x8 b3 = *(const bf16x8*)(hstep + 1536);

        const int jbase = g * 32 + step * 256 + q * 8;   // within j-half
        const float4 ce0 = *(const float4*)&e2lds[jbase];
        const float4 ce1 = *(const float4*)&e2lds[jbase + 4];
        const unsigned bits = (unsigned)abyte[step * 32];

        const float ev[8] = {ce0.x, ce0.y, ce0.z, ce0.w, ce1.x, ce1.y, ce1.z, ce1.w};
        bf16x8 afrag;
        #pragma unroll
        for (int jj = 0; jj < 8; ++jj) {
            float e = e1v + ev[jj];
            e = fmaxf(e, 0.2f * e);                      // leaky relu
            const float wv = ((bits >> jj) & 1u) ? __expf(e) : 0.f;
            zacc += wv;
            afrag[jj] = f2bf(wv);
        }

        accf[0] = __builtin_amdgcn_mfma_f32_16x16x32_bf16(afrag, b0, accf[0], 0, 0, 0);
        accf[1] = __builtin_amdgcn_mfma_f32_16x16x32_bf16(afrag, b1, accf[1], 0, 0, 0);
        accf[2] = __builtin_amdgcn_mfma_f32_16x16x32_bf16(afrag, b2, accf[2], 0, 0, 0);
        accf[3] = __builtin_amdgcn_mfma_f32_16x16x32_bf16(afrag, b3, accf[3], 0, 0, 0);
    }

    // Z stripe partial per row m
    zacc += __shfl_xor(zacc, 16, 64);
    zacc += __shfl_xor(zacc, 32, 64);
    if (lane < 16) zbuf[g][lane] = zacc;

    // numerator: C layout row=q*4+r, col=ft*16+m
    #pragma unroll
    for (int ft = 0; ft < 4; ++ft)
        #pragma unroll
        for (int r = 0; r < 4; ++r)
            atomicAdd(&obuf[q * 4 + r][ft * 16 + m], accf[ft][r]);
    __syncthreads();

    if (t < 16) {
        float Z = 0.f;
        #pragma unroll
        for (int gg = 0; gg < 8; ++gg) Z += zbuf[gg][t];
        zpart[((size_t)jh * 4 + hd) * N + i0 + t] = Z;
    }
    if (t < 256) {   // exclusive slice write: nbuf[jh][hd][it][16][64]
        const float4 v = ((const float4*)obuf)[t];
        ((float4*)nbuf)[(((size_t)jh * 4 + hd) * 256 + it) * 256 + t] = v;
    }
}

// Kernel 3: out[i][f] = 0.25 * sum_h (n0+n1)/(z0+z1)
__global__ __launch_bounds__(256) void gat_k3(const float* __restrict__ nbuf,
                                              const float* __restrict__ zpart,
                                              float* __restrict__ out) {
    const int v  = blockIdx.x * 256 + threadIdx.x;   // f4 index, 65536 total
    const int i  = v >> 4;
    const int it = i >> 4;
    const int r  = i & 15;
    const int fq = v & 15;
    const float4* nb = (const float4*)nbuf;
    float4 s = make_float4(0.f, 0.f, 0.f, 0.f);
    #pragma unroll
    for (int hd = 0; hd < HEADS; ++hd) {
        const float Z = zpart[(size_t)hd * N + i] + zpart[((size_t)4 + hd) * N + i];
        const float4 n0 = nb[((size_t)hd * 256 + it) * 256 + r * 16 + fq];
        const float4 n1 = nb[((size_t)(4 + hd) * 256 + it) * 256 + r * 16 + fq];
        const float inv = 0.25f / Z;
        s.x += (n0.x + n1.x) * inv;
        s.y += (n0.y + n1.y) * inv;
        s.z += (n0.z + n1.z) * inv;
        s.w += (n0.w + n1.w) * inv;
    }
    ((float4*)out)[v] = s;
}

extern "C" void kernel_launch(void* const* d_in, const int* in_sizes, int n_in,
                              void* d_out, int out_size, void* d_ws, size_t ws_size,
                              hipStream_t stream) {
    const float* x   = (const float*)d_in[0];
    const int*   adj = (const int*)d_in[1];
    const float* W   = (const float*)d_in[2];
    const float* a   = (const float*)d_in[3];
    float* out = (float*)d_out;

    short*    hF    = (short*)d_ws;                            // 2 MB
    float*    e1T   = (float*)(hF + (size_t)HEADS * FOUT * N); // 64 KB
    float*    e2T   = e1T + (size_t)HEADS * N;                 // 64 KB
    unsigned* adjb  = (unsigned*)(e2T + (size_t)HEADS * N);    // 2 MB
    float*    nbuf  = (float*)(adjb + (size_t)N * 128);        // 8 MB
    float*    zpart = nbuf + (size_t)2 * HEADS * N * FOUT;     // 128 KB

    gat_k1<<<1280, 256, 0, stream>>>(x, W, a, adj, hF, e1T, e2T, adjb);
    gat_k2<<<2048, 512, 0, stream>>>(hF, adjb, e1T, e2T, nbuf, zpart);
    gat_k3<<<256, 256, 0, stream>>>(nbuf, zpart, out);
}

// Round 7
// 180.267 us; speedup vs baseline: 1.1404x; 1.1404x over previous
//
#include <hip/hip_runtime.h>

#define N     4096
#define FIN   256
#define CC    256   // HEADS * F_OUT
#define HEADS 4
#define FOUT  64
#define XPITCH 266  // FIN+10 shorts = 133 dwords (odd) -> conflict-free
#define HPITCH 74   // 37 dwords (odd)
#define LOG2E 1.4426950408889634f

typedef __attribute__((ext_vector_type(8))) short bf16x8;
typedef __attribute__((ext_vector_type(4))) float f32x4;
typedef __attribute__((ext_vector_type(4))) unsigned u32x4;

// float -> bf16 (round-nearest-even)
__device__ inline short f2bf(float f) {
    unsigned u = __builtin_bit_cast(unsigned, f);
    unsigned r = u + 0x7fffu + ((u >> 16) & 1u);
    return (short)(r >> 16);
}
// RNE without final shift (keep in high hword)
__device__ inline unsigned rne_hi(float f) {
    unsigned u = __builtin_bit_cast(unsigned, f);
    return u + 0x7fffu + ((u >> 16) & 1u);
}
// two floats -> packed bf16 pair (lo in low hword)
__device__ inline unsigned pack_pair(float lo, float hi) {
    return __builtin_amdgcn_perm(rne_hi(hi), rne_hi(lo), 0x07060302);
}
// one attention weight: e2 pre-scaled by log2e, e1l pre-scaled
__device__ inline float wcalc(float e1l, float evl, unsigned bits, int jj) {
    const float el = e1l + evl;
    const float tt = fmaxf(el, 0.2f * el);    // leaky relu (scale-invariant)
    const float x  = exp2f(tt);               // v_exp_f32
    return ((bits >> jj) & 1u) ? x : 0.f;
}

// Kernel 1, fused:
//   blocks [0,256):    h = x@W via MFMA (one head x 64 n-rows) -> hF in
//                      fragment order + e1T/e2T wave-reduced; zeroes out.
//   blocks [256,1280): adj -> bitmask adjb, shfl-FREE: lane packs its own
//                      64 columns (16 int4 loads in flight), one uint2 store.
__global__ __launch_bounds__(256) void gat_k1(const float* __restrict__ x,
                                              const float* __restrict__ W,
                                              const float* __restrict__ a,
                                              const int* __restrict__ adj,
                                              short* __restrict__ hF,
                                              float* __restrict__ e1T,
                                              float* __restrict__ e2T,
                                              unsigned* __restrict__ adjb,
                                              float* __restrict__ out) {
    __shared__ __align__(16) short xs[64][XPITCH];    // 34.0 KB
    __shared__ __align__(16) short wts[64][XPITCH];   // 34.0 KB
    __shared__ __align__(16) short hbuf[64][HPITCH];  //  9.5 KB
    const int t    = threadIdx.x;
    const int bid  = blockIdx.x;
    const int lane = t & 63;
    const int w    = t >> 6;

    if (bid >= 256) {
        // ---- adj bitmask pack: one row per wave, lane-local bits ----
        const int row = (bid - 256) * 4 + w;
        const int4* base = (const int4*)(adj + (size_t)row * N) + lane * 16;
        unsigned dv[2];
        #pragma unroll
        for (int p = 0; p < 2; ++p) {
            int4 c[8];
            #pragma unroll
            for (int k = 0; k < 8; ++k) c[k] = base[p * 8 + k];   // 8 in flight
            unsigned d = 0;
            #pragma unroll
            for (int k = 0; k < 8; ++k) {
                d |= (c[k].x != 0 ? 1u : 0u) << (k * 4 + 0);
                d |= (c[k].y != 0 ? 1u : 0u) << (k * 4 + 1);
                d |= (c[k].z != 0 ? 1u : 0u) << (k * 4 + 2);
                d |= (c[k].w != 0 ? 1u : 0u) << (k * 4 + 3);
            }
            dv[p] = d;
        }
        *(uint2*)(adjb + (size_t)row * 128 + lane * 2) = make_uint2(dv[0], dv[1]);
        return;
    }

    // ---- GEMM block ----
    ((float4*)out)[bid * 256 + t] = make_float4(0.f, 0.f, 0.f, 0.f);

    const int hd = bid >> 6;
    const int n0 = (bid & 63) * 64;
    const int c0 = hd * 64;

    {   // stage x rows n0..n0+63 as bf16
        const float4* xsrc = (const float4*)(x + (size_t)n0 * FIN);
        #pragma unroll
        for (int it = 0; it < 16; ++it) {
            const int fi = it * 256 + t;
            const float4 v = xsrc[fi];
            short4 o;
            o.x = f2bf(v.x); o.y = f2bf(v.y); o.z = f2bf(v.z); o.w = f2bf(v.w);
            *(short4*)&xs[fi >> 6][(fi & 63) * 4] = o;
        }
    }
    {   // stage W^T column slice
        const int c  = t & 63;
        const int k4 = (t >> 6) * 4;
        #pragma unroll
        for (int it = 0; it < 16; ++it) {
            const int k = it * 16 + k4;
            short4 pk;
            pk.x = f2bf(W[(k + 0) * CC + c0 + c]);
            pk.y = f2bf(W[(k + 1) * CC + c0 + c]);
            pk.z = f2bf(W[(k + 2) * CC + c0 + c]);
            pk.w = f2bf(W[(k + 3) * CC + c0 + c]);
            *(short4*)&wts[c][k] = pk;
        }
    }
    __syncthreads();

    const int m = lane & 15;
    const int q = lane >> 4;

    f32x4 acc[4];
    #pragma unroll
    for (int ct = 0; ct < 4; ++ct) acc[ct] = (f32x4){0.f, 0.f, 0.f, 0.f};

    #pragma unroll
    for (int ks = 0; ks < 8; ++ks) {
        const bf16x8 af = *(const bf16x8*)&xs[w * 16 + m][ks * 32 + q * 8];
        #pragma unroll
        for (int ct = 0; ct < 4; ++ct) {
            const bf16x8 bf_ = *(const bf16x8*)&wts[ct * 16 + m][ks * 32 + q * 8];
            acc[ct] = __builtin_amdgcn_mfma_f32_16x16x32_bf16(af, bf_, acc[ct], 0, 0, 0);
        }
    }

    // e1/e2 from fp32 acc (C layout: row=q*4+r, col=ct*16+m)
    const float a1v[4] = {a[m], a[16 + m], a[32 + m], a[48 + m]};
    const float a2v[4] = {a[64 + m], a[80 + m], a[96 + m], a[112 + m]};
    #pragma unroll
    for (int r = 0; r < 4; ++r) {
        float s1 = 0.f, s2 = 0.f;
        #pragma unroll
        for (int ct = 0; ct < 4; ++ct) {
            s1 = fmaf(acc[ct][r], a1v[ct], s1);
            s2 = fmaf(acc[ct][r], a2v[ct], s2);
        }
        #pragma unroll
        for (int sh = 1; sh < 16; sh <<= 1) {
            s1 += __shfl_xor(s1, sh, 64);
            s2 += __shfl_xor(s2, sh, 64);
        }
        if (m == 0) {
            const int n = n0 + w * 16 + q * 4 + r;
            e1T[hd * N + n] = s1;
            e2T[hd * N + n] = s2;
        }
    }

    // transpose h tile to hbuf[c][n-local]
    #pragma unroll
    for (int ct = 0; ct < 4; ++ct)
        #pragma unroll
        for (int r = 0; r < 4; ++r)
            hbuf[ct * 16 + m][w * 16 + q * 4 + r] = f2bf(acc[ct][r]);
    __syncthreads();

    // write hF in fragment order: frag(jc, ft) lane lp holds
    // h[f=ft*16+(lp&15)][j = jc*32 + (lp>>4)*8 + 0..7]
    {
        const int lp = t & 63;
        const int ft = t >> 6;
        const int mm = lp & 15;
        const int qq = lp >> 4;
        #pragma unroll
        for (int c2 = 0; c2 < 2; ++c2) {
            const bf16x8 hv = *(const bf16x8*)&hbuf[ft * 16 + mm][c2 * 32 + qq * 8];
            const size_t jc = (size_t)(n0 >> 5) + c2;
            *(bf16x8*)(hF + ((((size_t)hd * 128 + jc) * 4 + ft) * 64 + lp) * 8) = hv;
        }
    }
}

// Kernel 2: masked-softmax aggregation via MFMA. 32 i-rows x one head x
// full j per block (grid 512, XCD-affine i-tiles). 8 waves = 8 j-stripes;
// Z completes in-block. SOFTWARE-PIPELINED: step s+1's b-frags / e2 / adj
// byte are loaded before step s's weight-gen VALU, so the MFMAs consume
// data loaded a full step (~latency) earlier.
__global__ __launch_bounds__(512, 4) void gat_k2(const short* __restrict__ hF,
                                                 const unsigned* __restrict__ adjb,
                                                 const float* __restrict__ e1T,
                                                 const float* __restrict__ e2T,
                                                 float* __restrict__ out) {
    __shared__ float obuf[32][64];                //  8 KB
    __shared__ float zbuf[8][32];                 //  1 KB
    __shared__ __align__(16) float e2lds[N];      // 16 KB (log2e-scaled)
    __shared__ unsigned adjlds[32 * 129];         // 16.5 KB (odd pitch)
    const int t    = threadIdx.x;
    const int lane = t & 63;
    const int g    = t >> 6;
    const int bid  = blockIdx.x;
    const int hd   = (bid >> 3) & 3;
    const int it   = (bid & 7) | ((bid >> 5) << 3);   // XCD-affine i-tile
    const int i0   = it * 32;
    const int m    = lane & 15;
    const int q    = lane >> 4;

    {   // zero numerator
        float* ob = &obuf[0][0];
        #pragma unroll
        for (int r = 0; r < 4; ++r) ob[t + r * 512] = 0.f;
    }
    {   // stage e2 (this head, all j), pre-scaled by log2e
        const float4* src = (const float4*)(e2T + (size_t)hd * N);
        float4* dst = (float4*)e2lds;
        float4 v0 = src[t], v1 = src[t + 512];
        v0.x *= LOG2E; v0.y *= LOG2E; v0.z *= LOG2E; v0.w *= LOG2E;
        v1.x *= LOG2E; v1.y *= LOG2E; v1.z *= LOG2E; v1.w *= LOG2E;
        dst[t] = v0; dst[t + 512] = v1;
    }
    {   // stage adj bits for 32 i-rows
        const unsigned* src = adjb + (size_t)i0 * 128;
        #pragma unroll
        for (int r = 0; r < 8; ++r) {
            const int idx = t + r * 512;
            adjlds[(idx >> 7) * 129 + (idx & 127)] = src[idx];
        }
    }
    __syncthreads();

    const float e1a = e1T[hd * N + i0 + m] * LOG2E;
    const float e1b = e1T[hd * N + i0 + 16 + m] * LOG2E;

    f32x4 accf[4], accg[4];
    #pragma unroll
    for (int ft = 0; ft < 4; ++ft) {
        accf[ft] = (f32x4){0.f, 0.f, 0.f, 0.f};
        accg[ft] = (f32x4){0.f, 0.f, 0.f, 0.f};
    }
    float zacc0 = 0.f, zacc1 = 0.f;

    const short* hbase = hF + (((size_t)hd * 128 + g) * 4 * 64 + lane) * 8;
    const unsigned char* abyte0 = ((const unsigned char*)adjlds) + m * 516 + g * 4 + q;
    const unsigned char* abyte1 = abyte0 + 16 * 516;

    // prologue: load step 0
    bf16x8 cb0 = *(const bf16x8*)(hbase);
    bf16x8 cb1 = *(const bf16x8*)(hbase + 512);
    bf16x8 cb2 = *(const bf16x8*)(hbase + 1024);
    bf16x8 cb3 = *(const bf16x8*)(hbase + 1536);
    const int jb0 = g * 32 + q * 8;
    float4 ce0 = *(const float4*)&e2lds[jb0];
    float4 ce1 = *(const float4*)&e2lds[jb0 + 4];
    unsigned cbits0 = (unsigned)abyte0[0];
    unsigned cbits1 = (unsigned)abyte1[0];

    for (int step = 0; step < 16; ++step) {
        // ---- prefetch step+1 (issued before this step's VALU) ----
        const int sn = (step < 15) ? step + 1 : 15;
        const short* hn = hbase + (size_t)sn * 16384;
        const bf16x8 nb0 = *(const bf16x8*)(hn);
        const bf16x8 nb1 = *(const bf16x8*)(hn + 512);
        const bf16x8 nb2 = *(const bf16x8*)(hn + 1024);
        const bf16x8 nb3 = *(const bf16x8*)(hn + 1536);
        const int jn = g * 32 + sn * 256 + q * 8;
        const float4 ne0 = *(const float4*)&e2lds[jn];
        const float4 ne1 = *(const float4*)&e2lds[jn + 4];
        const unsigned nbits0 = (unsigned)abyte0[sn * 32];
        const unsigned nbits1 = (unsigned)abyte1[sn * 32];

        // ---- weight gen for CURRENT step ----
        const float evl[8] = {ce0.x, ce0.y, ce0.z, ce0.w, ce1.x, ce1.y, ce1.z, ce1.w};
        u32x4 pk0, pk1;
        #pragma unroll
        for (int p = 0; p < 4; ++p) {
            const float wa0 = wcalc(e1a, evl[2 * p],     cbits0, 2 * p);
            const float wa1 = wcalc(e1a, evl[2 * p + 1], cbits0, 2 * p + 1);
            const float wb0 = wcalc(e1b, evl[2 * p],     cbits1, 2 * p);
            const float wb1 = wcalc(e1b, evl[2 * p + 1], cbits1, 2 * p + 1);
            zacc0 += wa0 + wa1;
            zacc1 += wb0 + wb1;
            pk0[p] = pack_pair(wa0, wa1);
            pk1[p] = pack_pair(wb0, wb1);
        }
        const bf16x8 af0 = __builtin_bit_cast(bf16x8, pk0);
        const bf16x8 af1 = __builtin_bit_cast(bf16x8, pk1);

        accf[0] = __builtin_amdgcn_mfma_f32_16x16x32_bf16(af0, cb0, accf[0], 0, 0, 0);
        accg[0] = __builtin_amdgcn_mfma_f32_16x16x32_bf16(af1, cb0, accg[0], 0, 0, 0);
        accf[1] = __builtin_amdgcn_mfma_f32_16x16x32_bf16(af0, cb1, accf[1], 0, 0, 0);
        accg[1] = __builtin_amdgcn_mfma_f32_16x16x32_bf16(af1, cb1, accg[1], 0, 0, 0);
        accf[2] = __builtin_amdgcn_mfma_f32_16x16x32_bf16(af0, cb2, accf[2], 0, 0, 0);
        accg[2] = __builtin_amdgcn_mfma_f32_16x16x32_bf16(af1, cb2, accg[2], 0, 0, 0);
        accf[3] = __builtin_amdgcn_mfma_f32_16x16x32_bf16(af0, cb3, accf[3], 0, 0, 0);
        accg[3] = __builtin_amdgcn_mfma_f32_16x16x32_bf16(af1, cb3, accg[3], 0, 0, 0);

        // rotate
        cb0 = nb0; cb1 = nb1; cb2 = nb2; cb3 = nb3;
        ce0 = ne0; ce1 = ne1;
        cbits0 = nbits0; cbits1 = nbits1;
    }

    // Z stripe partial per row
    zacc0 += __shfl_xor(zacc0, 16, 64);
    zacc0 += __shfl_xor(zacc0, 32, 64);
    zacc1 += __shfl_xor(zacc1, 16, 64);
    zacc1 += __shfl_xor(zacc1, 32, 64);
    if (lane < 16) {
        zbuf[g][lane]      = zacc0;
        zbuf[g][16 + lane] = zacc1;
    }

    // numerator: C layout row=q*4+r, col=ft*16+m
    #pragma unroll
    for (int ft = 0; ft < 4; ++ft)
        #pragma unroll
        for (int r = 0; r < 4; ++r) {
            atomicAdd(&obuf[q * 4 + r][ft * 16 + m], accf[ft][r]);
            atomicAdd(&obuf[16 + q * 4 + r][ft * 16 + m], accg[ft][r]);
        }
    __syncthreads();

    #pragma unroll
    for (int rep = 0; rep < 4; ++rep) {
        const int idx = t + rep * 512;
        const int ii  = idx >> 6;     // 0..31
        const int ff  = idx & 63;
        float Z = 0.f;
        #pragma unroll
        for (int gg = 0; gg < 8; ++gg) Z += zbuf[gg][ii];
        atomicAdd(&out[(size_t)(i0 + ii) * FOUT + ff], 0.25f * obuf[ii][ff] / Z);
    }
}

extern "C" void kernel_launch(void* const* d_in, const int* in_sizes, int n_in,
                              void* d_out, int out_size, void* d_ws, size_t ws_size,
                              hipStream_t stream) {
    const float* x   = (const float*)d_in[0];
    const int*   adj = (const int*)d_in[1];
    const float* W   = (const float*)d_in[2];
    const float* a   = (const float*)d_in[3];
    float* out = (float*)d_out;

    short*    hF   = (short*)d_ws;                           // 2 MB
    float*    e1T  = (float*)(hF + (size_t)HEADS * FOUT * N);
    float*    e2T  = e1T + (size_t)HEADS * N;
    unsigned* adjb = (unsigned*)(e2T + (size_t)HEADS * N);   // 2 MB

    gat_k1<<<1280, 256, 0, stream>>>(x, W, a, adj, hF, e1T, e2T, adjb, out);
    gat_k2<<<512, 512, 0, stream>>>(hF, adjb, e1T, e2T, out);
}

// Round 8
// 171.238 us; speedup vs baseline: 1.2006x; 1.0527x over previous
//
#include <hip/hip_runtime.h>

#define N     4096
#define FIN   256
#define CC    256   // HEADS * F_OUT
#define HEADS 4
#define FOUT  64
#define XPITCH 266  // FIN+10 shorts = 133 dwords (odd) -> conflict-free
#define HPITCH 74   // 37 dwords (odd)
#define LOG2E 1.4426950408889634f

typedef __attribute__((ext_vector_type(8))) short bf16x8;
typedef __attribute__((ext_vector_type(4))) float f32x4;
typedef __attribute__((ext_vector_type(4))) unsigned u32x4;

// float -> bf16 (round-nearest-even) — used in k1 only
__device__ inline short f2bf(float f) {
    unsigned u = __builtin_bit_cast(unsigned, f);
    unsigned r = u + 0x7fffu + ((u >> 16) & 1u);
    return (short)(r >> 16);
}
// two floats -> packed bf16 pair by TRUNCATION (1 v_perm). Softmax ratio
// cancels the systematic downward bias; error << threshold.
__device__ inline unsigned pack_trunc(float lo, float hi) {
    return __builtin_amdgcn_perm(__builtin_bit_cast(unsigned, hi),
                                 __builtin_bit_cast(unsigned, lo), 0x07060302);
}
// one attention weight: e1/e2 pre-scaled by log2e
__device__ inline float wcalc(float e1l, float evl, unsigned bits, int jj) {
    const float el = e1l + evl;
    const float tt = fmaxf(el, 0.2f * el);    // leaky relu (scale-invariant)
    const float x  = exp2f(tt);               // v_exp_f32
    return ((bits >> jj) & 1u) ? x : 0.f;
}

// Kernel 1, fused:
//   blocks [0,256):    h = x@W via MFMA (one head x 64 n-rows) -> hF in
//                      fragment order + e1T/e2T wave-reduced; zeroes out.
//   blocks [256,1280): adj -> bitmask adjb, shfl-free lane-local pack.
__global__ __launch_bounds__(256) void gat_k1(const float* __restrict__ x,
                                              const float* __restrict__ W,
                                              const float* __restrict__ a,
                                              const int* __restrict__ adj,
                                              short* __restrict__ hF,
                                              float* __restrict__ e1T,
                                              float* __restrict__ e2T,
                                              unsigned* __restrict__ adjb,
                                              float* __restrict__ out) {
    __shared__ __align__(16) short xs[64][XPITCH];    // 34.0 KB
    __shared__ __align__(16) short wts[64][XPITCH];   // 34.0 KB
    __shared__ __align__(16) short hbuf[64][HPITCH];  //  9.5 KB
    const int t    = threadIdx.x;
    const int bid  = blockIdx.x;
    const int lane = t & 63;
    const int w    = t >> 6;

    if (bid >= 256) {
        // ---- adj bitmask pack: one row per wave, lane-local bits ----
        const int row = (bid - 256) * 4 + w;
        const int4* base = (const int4*)(adj + (size_t)row * N) + lane * 16;
        unsigned dv[2];
        #pragma unroll
        for (int p = 0; p < 2; ++p) {
            int4 c[8];
            #pragma unroll
            for (int k = 0; k < 8; ++k) c[k] = base[p * 8 + k];   // 8 in flight
            unsigned d = 0;
            #pragma unroll
            for (int k = 0; k < 8; ++k) {
                d |= (c[k].x != 0 ? 1u : 0u) << (k * 4 + 0);
                d |= (c[k].y != 0 ? 1u : 0u) << (k * 4 + 1);
                d |= (c[k].z != 0 ? 1u : 0u) << (k * 4 + 2);
                d |= (c[k].w != 0 ? 1u : 0u) << (k * 4 + 3);
            }
            dv[p] = d;
        }
        *(uint2*)(adjb + (size_t)row * 128 + lane * 2) = make_uint2(dv[0], dv[1]);
        return;
    }

    // ---- GEMM block ----
    ((float4*)out)[bid * 256 + t] = make_float4(0.f, 0.f, 0.f, 0.f);

    const int hd = bid >> 6;
    const int n0 = (bid & 63) * 64;
    const int c0 = hd * 64;

    {   // stage x rows n0..n0+63 as bf16
        const float4* xsrc = (const float4*)(x + (size_t)n0 * FIN);
        #pragma unroll
        for (int it = 0; it < 16; ++it) {
            const int fi = it * 256 + t;
            const float4 v = xsrc[fi];
            short4 o;
            o.x = f2bf(v.x); o.y = f2bf(v.y); o.z = f2bf(v.z); o.w = f2bf(v.w);
            *(short4*)&xs[fi >> 6][(fi & 63) * 4] = o;
        }
    }
    {   // stage W^T column slice
        const int c  = t & 63;
        const int k4 = (t >> 6) * 4;
        #pragma unroll
        for (int it = 0; it < 16; ++it) {
            const int k = it * 16 + k4;
            short4 pk;
            pk.x = f2bf(W[(k + 0) * CC + c0 + c]);
            pk.y = f2bf(W[(k + 1) * CC + c0 + c]);
            pk.z = f2bf(W[(k + 2) * CC + c0 + c]);
            pk.w = f2bf(W[(k + 3) * CC + c0 + c]);
            *(short4*)&wts[c][k] = pk;
        }
    }
    __syncthreads();

    const int m = lane & 15;
    const int q = lane >> 4;

    f32x4 acc[4];
    #pragma unroll
    for (int ct = 0; ct < 4; ++ct) acc[ct] = (f32x4){0.f, 0.f, 0.f, 0.f};

    #pragma unroll
    for (int ks = 0; ks < 8; ++ks) {
        const bf16x8 af = *(const bf16x8*)&xs[w * 16 + m][ks * 32 + q * 8];
        #pragma unroll
        for (int ct = 0; ct < 4; ++ct) {
            const bf16x8 bf_ = *(const bf16x8*)&wts[ct * 16 + m][ks * 32 + q * 8];
            acc[ct] = __builtin_amdgcn_mfma_f32_16x16x32_bf16(af, bf_, acc[ct], 0, 0, 0);
        }
    }

    // e1/e2 from fp32 acc (C layout: row=q*4+r, col=ct*16+m)
    const float a1v[4] = {a[m], a[16 + m], a[32 + m], a[48 + m]};
    const float a2v[4] = {a[64 + m], a[80 + m], a[96 + m], a[112 + m]};
    #pragma unroll
    for (int r = 0; r < 4; ++r) {
        float s1 = 0.f, s2 = 0.f;
        #pragma unroll
        for (int ct = 0; ct < 4; ++ct) {
            s1 = fmaf(acc[ct][r], a1v[ct], s1);
            s2 = fmaf(acc[ct][r], a2v[ct], s2);
        }
        #pragma unroll
        for (int sh = 1; sh < 16; sh <<= 1) {
            s1 += __shfl_xor(s1, sh, 64);
            s2 += __shfl_xor(s2, sh, 64);
        }
        if (m == 0) {
            const int n = n0 + w * 16 + q * 4 + r;
            e1T[hd * N + n] = s1;
            e2T[hd * N + n] = s2;
        }
    }

    // transpose h tile to hbuf[c][n-local]
    #pragma unroll
    for (int ct = 0; ct < 4; ++ct)
        #pragma unroll
        for (int r = 0; r < 4; ++r)
            hbuf[ct * 16 + m][w * 16 + q * 4 + r] = f2bf(acc[ct][r]);
    __syncthreads();

    // write hF in fragment order: frag(jc, ft) lane lp holds
    // h[f=ft*16+(lp&15)][j = jc*32 + (lp>>4)*8 + 0..7]
    {
        const int lp = t & 63;
        const int ft = t >> 6;
        const int mm = lp & 15;
        const int qq = lp >> 4;
        #pragma unroll
        for (int c2 = 0; c2 < 2; ++c2) {
            const bf16x8 hv = *(const bf16x8*)&hbuf[ft * 16 + mm][c2 * 32 + qq * 8];
            const size_t jc = (size_t)(n0 >> 5) + c2;
            *(bf16x8*)(hF + ((((size_t)hd * 128 + jc) * 4 + ft) * 64 + lp) * 8) = hv;
        }
    }
}

// Kernel 2: masked-softmax aggregation via MFMA, occupancy-first.
// 16 i-rows x one head x full j per block; 8 waves = 8 j-stripes (16 steps
// each); ONE A-frag per wave. No manual pipelining — __launch_bounds__(512,8)
// gives 4 blocks/CU = 32 waves/CU and TLP hides L2/LDS latency. Grid 1024,
// XCD-affine i-tiles (4 head-blocks of an i-tile share hF/adjb in L2).
__global__ __launch_bounds__(512, 8) void gat_k2(const short* __restrict__ hF,
                                                 const unsigned* __restrict__ adjb,
                                                 const float* __restrict__ e1T,
                                                 const float* __restrict__ e2T,
                                                 float* __restrict__ out) {
    __shared__ float obuf[16][64];                //  4 KB
    __shared__ float zbuf[8][16];                 //  0.5 KB
    __shared__ __align__(16) float e2lds[N];      // 16 KB (log2e-scaled)
    __shared__ unsigned adjlds[16 * 129];         //  8.25 KB (odd pitch)
    const int t    = threadIdx.x;
    const int lane = t & 63;
    const int g    = t >> 6;                      // j-stripe 0..7
    const int bid  = blockIdx.x;
    const int hd   = (bid >> 3) & 3;
    const int it   = (bid & 7) | ((bid >> 5) << 3);   // XCD-affine i-tile
    const int i0   = it * 16;
    const int m    = lane & 15;
    const int q    = lane >> 4;

    {   float* ob = &obuf[0][0]; ob[t] = 0.f; ob[t + 512] = 0.f; }
    {   // stage e2 (this head, all j), pre-scaled by log2e
        const float4* src = (const float4*)(e2T + (size_t)hd * N);
        float4* dst = (float4*)e2lds;
        float4 v0 = src[t], v1 = src[t + 512];
        v0.x *= LOG2E; v0.y *= LOG2E; v0.z *= LOG2E; v0.w *= LOG2E;
        v1.x *= LOG2E; v1.y *= LOG2E; v1.z *= LOG2E; v1.w *= LOG2E;
        dst[t] = v0; dst[t + 512] = v1;
    }
    {   // stage adj bits for 16 i-rows (128 dw/row, 129-dw pitch)
        const unsigned* src = adjb + (size_t)i0 * 128;
        #pragma unroll
        for (int r = 0; r < 4; ++r) {
            const int idx = t + r * 512;
            adjlds[(idx >> 7) * 129 + (idx & 127)] = src[idx];
        }
    }
    __syncthreads();

    const float e1v = e1T[hd * N + i0 + m] * LOG2E;

    f32x4 accf[4];
    #pragma unroll
    for (int ft = 0; ft < 4; ++ft) accf[ft] = (f32x4){0.f, 0.f, 0.f, 0.f};
    float zacc = 0.f;

    // chunk jc = g + step*8; layout hF[hd][jc][ft][lane][8]
    const short* hbase = hF + (((size_t)hd * 128 + g) * 256 + lane) * 8;
    const unsigned char* abyte = ((const unsigned char*)adjlds) + m * 516 + g * 4 + q;

    for (int step = 0; step < 16; ++step) {
        const short* hstep = hbase + (size_t)step * 16384;   // 8 chunks * 2048
        const bf16x8 b0 = *(const bf16x8*)(hstep);
        const bf16x8 b1 = *(const bf16x8*)(hstep + 512);
        const bf16x8 b2 = *(const bf16x8*)(hstep + 1024);
        const bf16x8 b3 = *(const bf16x8*)(hstep + 1536);

        const int jbase = g * 32 + step * 256 + q * 8;
        const float4 ce0 = *(const float4*)&e2lds[jbase];
        const float4 ce1 = *(const float4*)&e2lds[jbase + 4];
        const unsigned bits = (unsigned)abyte[step * 32];

        const float evl[8] = {ce0.x, ce0.y, ce0.z, ce0.w, ce1.x, ce1.y, ce1.z, ce1.w};
        u32x4 pk;
        #pragma unroll
        for (int p = 0; p < 4; ++p) {
            const float w0 = wcalc(e1v, evl[2 * p],     bits, 2 * p);
            const float w1 = wcalc(e1v, evl[2 * p + 1], bits, 2 * p + 1);
            zacc += w0 + w1;
            pk[p] = pack_trunc(w0, w1);
        }
        const bf16x8 afrag = __builtin_bit_cast(bf16x8, pk);

        accf[0] = __builtin_amdgcn_mfma_f32_16x16x32_bf16(afrag, b0, accf[0], 0, 0, 0);
        accf[1] = __builtin_amdgcn_mfma_f32_16x16x32_bf16(afrag, b1, accf[1], 0, 0, 0);
        accf[2] = __builtin_amdgcn_mfma_f32_16x16x32_bf16(afrag, b2, accf[2], 0, 0, 0);
        accf[3] = __builtin_amdgcn_mfma_f32_16x16x32_bf16(afrag, b3, accf[3], 0, 0, 0);
    }

    // Z stripe partial per row m
    zacc += __shfl_xor(zacc, 16, 64);
    zacc += __shfl_xor(zacc, 32, 64);
    if (lane < 16) zbuf[g][lane] = zacc;

    // numerator: C layout row=q*4+r, col=ft*16+m
    #pragma unroll
    for (int ft = 0; ft < 4; ++ft)
        #pragma unroll
        for (int r = 0; r < 4; ++r)
            atomicAdd(&obuf[q * 4 + r][ft * 16 + m], accf[ft][r]);
    __syncthreads();

    #pragma unroll
    for (int rep = 0; rep < 2; ++rep) {
        const int idx = t + rep * 512;
        const int ii  = idx >> 6;     // 0..15
        const int ff  = idx & 63;
        float Z = 0.f;
        #pragma unroll
        for (int gg = 0; gg < 8; ++gg) Z += zbuf[gg][ii];
        atomicAdd(&out[(size_t)(i0 + ii) * FOUT + ff], 0.25f * obuf[ii][ff] / Z);
    }
}

extern "C" void kernel_launch(void* const* d_in, const int* in_sizes, int n_in,
                              void* d_out, int out_size, void* d_ws, size_t ws_size,
                              hipStream_t stream) {
    const float* x   = (const float*)d_in[0];
    const int*   adj = (const int*)d_in[1];
    const float* W   = (const float*)d_in[2];
    const float* a   = (const float*)d_in[3];
    float* out = (float*)d_out;

    short*    hF   = (short*)d_ws;                           // 2 MB
    float*    e1T  = (float*)(hF + (size_t)HEADS * FOUT * N);
    float*    e2T  = e1T + (size_t)HEADS * N;
    unsigned* adjb = (unsigned*)(e2T + (size_t)HEADS * N);   // 2 MB

    gat_k1<<<1280, 256, 0, stream>>>(x, W, a, adj, hF, e1T, e2T, adjb, out);
    gat_k2<<<1024, 512, 0, stream>>>(hF, adjb, e1T, e2T, out);
}